// Round 2
// baseline (964.157 us; speedup 1.0000x reference)
//
#include <hip/hip_runtime.h>
#include <hip/hip_bf16.h>

// AnomalyAttention: B=16, L=512, H=8, E=D=64. float32 in/out, f32 compute.
// out[b,l,h,d] = sum_s fused[b,h,l,s] * V[b,s,h,d]
//   series = causal softmax(QK^T/8); prior = row-normalized Gaussian (FULL row,
//   non-causal); fused = gate*series + (1-gate)*prior, renormalized over full s.

#define B_ 16
#define L_ 512
#define H_ 8
#define E_ 64

__device__ __forceinline__ float wave_max(float v) {
    #pragma unroll
    for (int off = 32; off > 0; off >>= 1) v = fmaxf(v, __shfl_xor(v, off, 64));
    return v;
}
__device__ __forceinline__ float wave_sum(float v) {
    #pragma unroll
    for (int off = 32; off > 0; off >>= 1) v += __shfl_xor(v, off, 64);
    return v;
}

__global__ __launch_bounds__(256) void anomaly_attn(
    const float* __restrict__ Q, const float* __restrict__ K,
    const float* __restrict__ V, const float* __restrict__ Sig,
    const float* __restrict__ Gate, float* __restrict__ Out)
{
    __shared__ __align__(16) float qbuf[4][64];
    __shared__ __align__(16) float wbuf[4][512];

    const int tid  = threadIdx.x;
    const int lane = tid & 63;
    const int wid  = tid >> 6;

    const int bid = blockIdx.x;          // ((b*H + h) * (L/4) + lt)
    const int lt  = bid & (L_ / 4 - 1);  // L/4 = 128
    const int bh  = bid >> 7;
    const int h   = bh & (H_ - 1);
    const int b   = bh >> 3;
    const int l   = lt * 4 + wid;

    // base offset for [b, *, h, *]: element = bh_off + s*H_*64 + e
    const size_t bh_off = ((size_t)b * L_ * H_ + h) * 64;
    const size_t row_stride = (size_t)H_ * 64;   // 512 floats between s rows

    // ---- load Q row into LDS (per-wave buffer) ----
    qbuf[wid][lane] = Q[bh_off + (size_t)l * row_stride + lane];
    __syncthreads();

    // ---- scores (causal): lane handles s = lane*8 .. lane*8+7 ----
    const float scale = 0.125f;  // 1/sqrt(64)
    const int s0 = lane * 8;
    float sc[8];
    #pragma unroll
    for (int j = 0; j < 8; ++j) {
        const int s = s0 + j;
        if (s <= l) {
            const float4* Krow = (const float4*)(K + bh_off + (size_t)s * row_stride);
            const float4* qp   = (const float4*)qbuf[wid];
            float acc = 0.f;
            #pragma unroll
            for (int e4 = 0; e4 < 16; ++e4) {
                float4 kv = Krow[e4];
                float4 qv = qp[e4];
                acc = fmaf(qv.x, kv.x, acc);
                acc = fmaf(qv.y, kv.y, acc);
                acc = fmaf(qv.z, kv.z, acc);
                acc = fmaf(qv.w, kv.w, acc);
            }
            sc[j] = acc * scale;
        } else {
            sc[j] = -INFINITY;
        }
    }

    // ---- causal softmax over s<=l ----
    float m = -INFINITY;
    #pragma unroll
    for (int j = 0; j < 8; ++j) m = fmaxf(m, sc[j]);
    m = wave_max(m);
    float es[8];
    float ssum = 0.f;
    #pragma unroll
    for (int j = 0; j < 8; ++j) {
        es[j] = (s0 + j <= l) ? __expf(sc[j] - m) : 0.f;
        ssum += es[j];
    }
    ssum = wave_sum(ssum);
    const float inv_ssum = 1.f / ssum;

    // ---- Gaussian prior over FULL row ----
    const float sgv = Sig[((size_t)b * L_ + l) * H_ + h];
    float sg = 1.f / (1.f + __expf(-5.f * sgv)) + 1e-5f;
    sg = exp2f(sg * 1.5849625007211562f) - 1.f;       // 3^sg - 1
    const float invs   = 0.3989422804014327f / sg;    // 1/(sqrt(2pi)*sig)
    const float inv2s2 = 0.5f / (sg * sg);
    float pr[8];
    float psum = 0.f;
    #pragma unroll
    for (int j = 0; j < 8; ++j) {
        const float d = (float)(l - (s0 + j));
        pr[j] = invs * __expf(-d * d * inv2s2);
        psum += pr[j];
    }
    psum = wave_sum(psum);
    const float invp = 1.f / (psum + 1e-8f);

    // ---- gated fuse + renorm over full row ----
    float g = Gate[h];
    g = 1.f / (1.f + __expf(-g));
    const float gc = 1.f - g;
    float fsum = 0.f;
    #pragma unroll
    for (int j = 0; j < 8; ++j) {
        sc[j] = g * es[j] * inv_ssum + gc * pr[j] * invp;
        fsum += sc[j];
    }
    fsum = wave_sum(fsum);
    const float invf = 1.f / (fsum + 1e-8f);
    #pragma unroll
    for (int j = 0; j < 8; ++j) wbuf[wid][s0 + j] = sc[j] * invf;
    __syncthreads();

    // ---- PV: lane = d, sum over all s (prior part is non-causal!) ----
    const float* Vb = V + bh_off;
    float acc = 0.f;
    for (int s = 0; s < L_; s += 4) {
        float4 w4 = *(const float4*)&wbuf[wid][s];
        acc = fmaf(w4.x, Vb[(size_t)(s    ) * row_stride + lane], acc);
        acc = fmaf(w4.y, Vb[(size_t)(s + 1) * row_stride + lane], acc);
        acc = fmaf(w4.z, Vb[(size_t)(s + 2) * row_stride + lane], acc);
        acc = fmaf(w4.w, Vb[(size_t)(s + 3) * row_stride + lane], acc);
    }

    // out[b,l,h,d]
    Out[bh_off + (size_t)l * row_stride + lane] = acc;
}

extern "C" void kernel_launch(void* const* d_in, const int* in_sizes, int n_in,
                              void* d_out, int out_size, void* d_ws, size_t ws_size,
                              hipStream_t stream) {
    const float* Q    = (const float*)d_in[0];
    const float* K    = (const float*)d_in[1];
    const float* V    = (const float*)d_in[2];
    const float* Sig  = (const float*)d_in[3];
    const float* Gate = (const float*)d_in[4];
    // d_in[5] = attn_mask: deterministic causal triu — not read.
    float* Out = (float*)d_out;

    dim3 grid(B_ * H_ * (L_ / 4));   // 16384 blocks, one (b,h,4-row) tile each
    anomaly_attn<<<grid, 256, 0, stream>>>(Q, K, V, Sig, Gate, Out);
}

// Round 3
// 380.996 us; speedup vs baseline: 2.5306x; 2.5306x over previous
//
#include <hip/hip_runtime.h>

// AnomalyAttention: B=16, L=512, H=8, E=D=64. float32 in/out, f32 compute.
// Single-pass streaming form (linearity trick):
//   out = [ g*(e@V)/E + (1-g)*(p@V)/(P+1e-8) ] / (Sf + 1e-8),
//   Sf = g + (1-g)*P/(P+1e-8);  e = exp(QK^T/8) causal (no max-sub needed),
//   p = Gaussian prior (full row). E,P are per-row sums of e,p.

#define B_ 16
#define L_ 512
#define H_ 8
#define ROWS 8                 // q-rows per wave
#define WAVES 4
#define TM (ROWS * WAVES)      // 32 q-rows per block
#define NLT (L_ / TM)          // 16 l-tiles per (b,h)
#define NST (L_ / 64)          // 8 s-tiles of 64

__device__ __forceinline__ float wave_sum(float v) {
    #pragma unroll
    for (int off = 32; off > 0; off >>= 1) v += __shfl_xor(v, off, 64);
    return v;
}

__global__ __launch_bounds__(256) void anomaly_attn(
    const float* __restrict__ Q, const float* __restrict__ K,
    const float* __restrict__ V, const float* __restrict__ Sig,
    const float* __restrict__ Gate, float* __restrict__ Out)
{
    // per-wave (e,p) staging tile: lane=s writes, lane=d broadcast-reads
    __shared__ __align__(16) float wb[WAVES][ROWS][64][2];   // 16 KB

    const int tid  = threadIdx.x;
    const int lane = tid & 63;
    const int wid  = __builtin_amdgcn_readfirstlane(tid >> 6);

    // blockIdx = t*128 + bh  -> same-bh blocks stride 128 (mod 8 == 0): same XCD
    const int idx = blockIdx.x;
    const int bh  = idx & (B_ * H_ - 1);
    const int t   = idx >> 7;
    const int h   = bh & (H_ - 1);
    const int b   = bh >> 3;
    const int l0  = t * TM + wid * ROWS;          // wave-uniform

    const size_t bh_off = ((size_t)b * L_ * H_ + h) * 64;
    const float* __restrict__ Qw = Q + bh_off + (size_t)l0 * 512;  // uniform base
    const float* __restrict__ Kb = K + bh_off;
    const float* __restrict__ Vb = V + bh_off;

    // per-row prior constants (wave-uniform)
    float invs[ROWS], i2s2[ROWS];
    #pragma unroll
    for (int r = 0; r < ROWS; ++r) {
        const float sgv = Sig[((size_t)b * L_ + (l0 + r)) * H_ + h];
        float sg = 1.f / (1.f + __expf(-5.f * sgv)) + 1e-5f;
        sg = exp2f(sg * 1.5849625007211562f) - 1.f;   // 3^sg - 1
        invs[r] = 0.3989422804014327f / sg;
        i2s2[r] = 0.5f / (sg * sg);
    }

    float accA[ROWS] = {}, accB[ROWS] = {}, eP[ROWS] = {}, pP[ROWS] = {};

    for (int tile = 0; tile < NST; ++tile) {
        const int s0 = tile * 64;
        const int s  = s0 + lane;                 // lane = s within tile
        const bool live = (s0 <= l0 + ROWS - 1);  // wave-uniform causal skip

        // ---- phase A: scores -> e, prior -> p (lane = s) ----
        float ev[ROWS];
        if (live) {
            float4 kv[16];
            const float4* Krow = (const float4*)(Kb + (size_t)s * 512);
            #pragma unroll
            for (int i = 0; i < 16; ++i) kv[i] = Krow[i];
            #pragma unroll
            for (int r = 0; r < ROWS; ++r) {
                const float4* qp = (const float4*)(Qw + (size_t)r * 512); // uniform -> s_load
                float acc = 0.f;
                #pragma unroll
                for (int i = 0; i < 16; ++i) {
                    const float4 q4 = qp[i];
                    acc = fmaf(q4.x, kv[i].x, acc);
                    acc = fmaf(q4.y, kv[i].y, acc);
                    acc = fmaf(q4.z, kv[i].z, acc);
                    acc = fmaf(q4.w, kv[i].w, acc);
                }
                const float e = __expf(acc * 0.125f);
                ev[r] = (s <= l0 + r) ? e : 0.f;
            }
        } else {
            #pragma unroll
            for (int r = 0; r < ROWS; ++r) ev[r] = 0.f;
        }
        #pragma unroll
        for (int r = 0; r < ROWS; ++r) {
            const float d = (float)(l0 + r - s);
            const float p = invs[r] * __expf(-d * d * i2s2[r]);
            eP[r] += ev[r];
            pP[r] += p;
            float2 w2; w2.x = ev[r]; w2.y = p;
            *(float2*)&wb[wid][r][lane][0] = w2;   // bank-even b64 write
        }
        asm volatile("s_waitcnt lgkmcnt(0)" ::: "memory");  // intra-wave LDS fence

        // ---- phase B: accumulate e@V and p@V (lane = d) ----
        if (live) {
            for (int ss = 0; ss < 64; ss += 2) {
                const float v0 = Vb[(size_t)(s0 + ss    ) * 512 + lane];
                const float v1 = Vb[(size_t)(s0 + ss + 1) * 512 + lane];
                #pragma unroll
                for (int r = 0; r < ROWS; ++r) {
                    const float4 w4 = *(const float4*)&wb[wid][r][ss][0]; // broadcast
                    accA[r] = fmaf(w4.x, v0, accA[r]);
                    accB[r] = fmaf(w4.y, v0, accB[r]);
                    accA[r] = fmaf(w4.z, v1, accA[r]);
                    accB[r] = fmaf(w4.w, v1, accB[r]);
                }
            }
        } else {  // fully-masked tile: e==0, only the prior accumulates
            for (int ss = 0; ss < 64; ss += 2) {
                const float v0 = Vb[(size_t)(s0 + ss    ) * 512 + lane];
                const float v1 = Vb[(size_t)(s0 + ss + 1) * 512 + lane];
                #pragma unroll
                for (int r = 0; r < ROWS; ++r) {
                    const float4 w4 = *(const float4*)&wb[wid][r][ss][0];
                    accB[r] = fmaf(w4.y, v0, accB[r]);
                    accB[r] = fmaf(w4.w, v1, accB[r]);
                }
            }
        }
        asm volatile("s_waitcnt lgkmcnt(0)" ::: "memory");  // WAR fence before next tile
    }

    // ---- epilogue: reductions + per-row scalar combine ----
    float g = Gate[h];
    g = 1.f / (1.f + __expf(-g));
    #pragma unroll
    for (int r = 0; r < ROWS; ++r) {
        const float E = wave_sum(eP[r]);
        const float P = wave_sum(pP[r]);
        const float cA = g / E;                    // E > 0 (diagonal term always live)
        const float cB = (1.f - g) / (P + 1e-8f);
        const float Sf = g + (1.f - g) * (P / (P + 1e-8f));
        const float o  = (cA * accA[r] + cB * accB[r]) / (Sf + 1e-8f);
        Out[bh_off + (size_t)(l0 + r) * 512 + lane] = o;
    }
}

extern "C" void kernel_launch(void* const* d_in, const int* in_sizes, int n_in,
                              void* d_out, int out_size, void* d_ws, size_t ws_size,
                              hipStream_t stream) {
    const float* Q    = (const float*)d_in[0];
    const float* K    = (const float*)d_in[1];
    const float* V    = (const float*)d_in[2];
    const float* Sig  = (const float*)d_in[3];
    const float* Gate = (const float*)d_in[4];
    // d_in[5] = attn_mask: deterministic causal triu — not read.
    float* Out = (float*)d_out;

    dim3 grid(NLT * B_ * H_);   // 2048 blocks: idx = t*128 + bh (XCD-affine)
    anomaly_attn<<<grid, 256, 0, stream>>>(Q, K, V, Sig, Gate, Out);
}

// Round 4
// 144.719 us; speedup vs baseline: 6.6623x; 2.6327x over previous
//
#include <hip/hip_runtime.h>

// AnomalyAttention: B=16, L=512, H=8, E=D=64. f32 in/out, bf16 MFMA compute.
// out = [ g*(e@V)/E + (1-g)*(p@V)/(P+1e-8) ] / (Sf + 1e-8),
//   Sf = g + (1-g)*P/(P+1e-8); e = exp(QK^T/8) causal (no max-sub needed),
//   p = Gaussian prior (full row); E,P per-row sums (E from bf16-rounded e).
// Block = 64 q-rows (4 waves x 16), streams 8 s-tiles of 64.
// MFMA 16x16x32 bf16 layouts (m120-verified):
//   A[m=lane&15][k=quad*8+j]  B[k=quad*8+j][n=lane&15]  D[row=quad*4+reg][col=lane&15]

#define B_ 16
#define L_ 512
#define H_ 8

#define KST 72   // K LDS row stride (shorts): 144B, 16B-aligned
#define VST 72   // V^T LDS row stride (shorts)
#define WST 68   // W_ep LDS row stride (dwords): 272B, 16B-aligned

typedef __attribute__((ext_vector_type(8))) short bf16x8;
typedef __attribute__((ext_vector_type(4))) float f32x4;
union FR { bf16x8 v; unsigned u[4]; };

__device__ __forceinline__ unsigned bfbits(float x) {
    union { float f; unsigned u; } c; c.f = x;
    return (c.u + 0x7FFFu + ((c.u >> 16) & 1u)) >> 16;
}
__device__ __forceinline__ float bfval(unsigned b) {
    union { unsigned u; float f; } c; c.u = b << 16; return c.f;
}
__device__ __forceinline__ float wsum16(float v) {
    #pragma unroll
    for (int off = 1; off < 16; off <<= 1) v += __shfl_xor(v, off, 64);
    return v;
}

__global__ __launch_bounds__(256, 4) void anomaly_attn(
    const float* __restrict__ Q, const float* __restrict__ K,
    const float* __restrict__ V, const float* __restrict__ Sig,
    const float* __restrict__ Gate, float* __restrict__ Out)
{
    __shared__ unsigned short Klds[64 * KST];   // 9216 B
    __shared__ unsigned short Vlds[64 * VST];   // 9216 B (V^T, granule-swizzled)
    __shared__ unsigned       Wep[4 * 16 * WST];// 17408 B (packed e|p<<16, bf16)

    const int tid  = threadIdx.x;
    const int lane = tid & 63;
    const int wid  = tid >> 6;
    const int quad = lane >> 4;
    const int c16  = lane & 15;

    const int idx = blockIdx.x;           // t*128 + bh (XCD-affine for same t)
    const int bh  = idx & 127;
    const int t   = idx >> 7;
    const int h   = bh & 7, b = bh >> 3;
    const int l0  = t * 64;
    const int l0w = l0 + wid * 16;

    const size_t bh_off = ((size_t)b * L_ * H_ + h) * 64;
    const float* __restrict__ Qb = Q + bh_off;
    const float* __restrict__ Kb = K + bh_off;
    const float* __restrict__ Vb = V + bh_off;

    // ---- Q A-frags (k = 64 -> 2 k-steps), held in registers ----
    bf16x8 qf[2];
    {
        const float* qrow = Qb + (size_t)(l0w + c16) * 512;
        #pragma unroll
        for (int ks = 0; ks < 2; ++ks) {
            const float4 a = *(const float4*)(qrow + ks * 32 + quad * 8);
            const float4 c = *(const float4*)(qrow + ks * 32 + quad * 8 + 4);
            FR f;
            f.u[0] = bfbits(a.x) | (bfbits(a.y) << 16);
            f.u[1] = bfbits(a.z) | (bfbits(a.w) << 16);
            f.u[2] = bfbits(c.x) | (bfbits(c.y) << 16);
            f.u[3] = bfbits(c.z) | (bfbits(c.w) << 16);
            qf[ks] = f.v;
        }
    }

    // ---- per-row prior constants (rows l0w + quad*4 + reg) ----
    float invs[4], i2s2[4], eP[4], pP[4];
    #pragma unroll
    for (int reg = 0; reg < 4; ++reg) {
        const int l = l0w + quad * 4 + reg;
        const float sgv = Sig[((size_t)b * L_ + l) * H_ + h];
        float sg = 1.f / (1.f + __expf(-5.f * sgv)) + 1e-5f;
        sg = exp2f(sg * 1.5849625007211562f) - 1.f;       // 3^sg - 1
        invs[reg] = 0.3989422804014327f / sg;
        i2s2[reg] = (0.5f / (sg * sg)) * 1.44269504088896f;  // folded log2(e)
        eP[reg] = 0.f; pP[reg] = 0.f;
    }

    f32x4 accA[4], accB[4];
    #pragma unroll
    for (int nt = 0; nt < 4; ++nt) { accA[nt] = (f32x4)0.f; accB[nt] = (f32x4)0.f; }

    // staging maps
    const int kr  = tid >> 2, kcb = tid & 3;   // K: row, 16-col chunk
    const int srp = tid >> 3, scb = tid & 7;   // V: s-row-pair, 8-col chunk

    unsigned* __restrict__ wrow = &Wep[wid * 16 * WST];  // wave-private

    for (int tile = 0; tile < 8; ++tile) {
        const int s0 = tile * 64;
        const bool live = (tile <= t);
        const bool diag = (tile == t);
        __syncthreads();   // prior tile's K/V reads complete

        if (live) {  // stage K tile -> bf16 LDS [s][e]
            const float* kp = Kb + (size_t)(s0 + kr) * 512 + kcb * 16;
            const float4 a = ((const float4*)kp)[0];
            const float4 c = ((const float4*)kp)[1];
            const float4 d = ((const float4*)kp)[2];
            const float4 e = ((const float4*)kp)[3];
            uint4 w0, w1;
            w0.x = bfbits(a.x) | (bfbits(a.y) << 16);
            w0.y = bfbits(a.z) | (bfbits(a.w) << 16);
            w0.z = bfbits(c.x) | (bfbits(c.y) << 16);
            w0.w = bfbits(c.z) | (bfbits(c.w) << 16);
            w1.x = bfbits(d.x) | (bfbits(d.y) << 16);
            w1.y = bfbits(d.z) | (bfbits(d.w) << 16);
            w1.z = bfbits(e.x) | (bfbits(e.y) << 16);
            w1.w = bfbits(e.z) | (bfbits(e.w) << 16);
            uint4* dst = (uint4*)&Klds[kr * KST + kcb * 16];
            dst[0] = w0; dst[1] = w1;
        }
        {   // stage V tile -> bf16 LDS transposed [d][s], XOR-granule swizzle
            const float* vp = Vb + (size_t)(s0 + 2 * srp) * 512 + scb * 8;
            const float4 a0 = ((const float4*)vp)[0];
            const float4 a1 = ((const float4*)vp)[1];
            const float4 b0 = ((const float4*)(vp + 512))[0];
            const float4 b1 = ((const float4*)(vp + 512))[1];
            const float lo[8] = {a0.x,a0.y,a0.z,a0.w,a1.x,a1.y,a1.z,a1.w};
            const float hi[8] = {b0.x,b0.y,b0.z,b0.w,b1.x,b1.y,b1.z,b1.w};
            const int gp  = (srp >> 2) ^ scb;   // swizzled granule (8 shorts)
            const int rpl = srp & 3;            // dword within granule
            #pragma unroll
            for (int i = 0; i < 8; ++i) {
                const int d = scb * 8 + i;
                unsigned* p = (unsigned*)&Vlds[d * VST + (gp << 3)];
                p[rpl] = bfbits(lo[i]) | (bfbits(hi[i]) << 16);
            }
        }
        __syncthreads();

        // ---- scores MFMA + elementwise -> packed (e,p) into W_ep ----
        if (live) {
            f32x4 sacc[4];
            #pragma unroll
            for (int nt = 0; nt < 4; ++nt) sacc[nt] = (f32x4)0.f;
            #pragma unroll
            for (int nt = 0; nt < 4; ++nt) {
                #pragma unroll
                for (int ks = 0; ks < 2; ++ks) {
                    const bf16x8 kf = *(const bf16x8*)&Klds[(nt*16 + c16)*KST + ks*32 + quad*8];
                    sacc[nt] = __builtin_amdgcn_mfma_f32_16x16x32_bf16(qf[ks], kf, sacc[nt], 0, 0, 0);
                }
            }
            #pragma unroll
            for (int nt = 0; nt < 4; ++nt) {
                const int scol = s0 + nt * 16 + c16;
                #pragma unroll
                for (int reg = 0; reg < 4; ++reg) {
                    const int lrow = l0w + quad * 4 + reg;
                    float e = exp2f(sacc[nt][reg] * 0.180336880110323f); // exp(s/8)
                    if (diag && scol > lrow) e = 0.f;
                    const float dd = (float)(lrow - scol);
                    const float p = invs[reg] * exp2f(-dd * dd * i2s2[reg]);
                    const unsigned eb = bfbits(e), pb = bfbits(p);
                    eP[reg] += bfval(eb);          // sums match MFMA operand exactly
                    pP[reg] += bfval(pb);
                    wrow[(quad*4 + reg)*WST + nt*16 + c16] = eb | (pb << 16);
                }
            }
        } else {  // prior-only tile
            #pragma unroll
            for (int nt = 0; nt < 4; ++nt) {
                const int scol = s0 + nt * 16 + c16;
                #pragma unroll
                for (int reg = 0; reg < 4; ++reg) {
                    const int lrow = l0w + quad * 4 + reg;
                    const float dd = (float)(lrow - scol);
                    const float p = invs[reg] * exp2f(-dd * dd * i2s2[reg]);
                    const unsigned pb = bfbits(p);
                    pP[reg] += bfval(pb);
                    wrow[(quad*4 + reg)*WST + nt*16 + c16] = pb << 16;
                }
            }
        }
        asm volatile("s_waitcnt lgkmcnt(0)" ::: "memory");

        // ---- PV MFMAs: A = W_ep rows (A-layout re-read), B = V^T tiles ----
        bf16x8 ef[2], pf[2];
        #pragma unroll
        for (int ks = 0; ks < 2; ++ks) {
            const unsigned* src = &wrow[c16 * WST + ks * 32 + quad * 8];
            const uint4 p0 = *(const uint4*)src;
            const uint4 p1 = *((const uint4*)src + 1);
            FR fe, fp;
            fe.u[0] = (p0.x & 0xFFFFu) | (p0.y << 16);
            fe.u[1] = (p0.z & 0xFFFFu) | (p0.w << 16);
            fe.u[2] = (p1.x & 0xFFFFu) | (p1.y << 16);
            fe.u[3] = (p1.z & 0xFFFFu) | (p1.w << 16);
            fp.u[0] = (p0.x >> 16) | (p0.y & 0xFFFF0000u);
            fp.u[1] = (p0.z >> 16) | (p0.w & 0xFFFF0000u);
            fp.u[2] = (p1.x >> 16) | (p1.y & 0xFFFF0000u);
            fp.u[3] = (p1.z >> 16) | (p1.w & 0xFFFF0000u);
            ef[ks] = fe.v; pf[ks] = fp.v;
        }
        #pragma unroll
        for (int nt = 0; nt < 4; ++nt) {
            const int d   = nt * 16 + c16;
            const int dg7 = (d >> 3) & 7;
            #pragma unroll
            for (int ks = 0; ks < 2; ++ks) {
                const int g2 = ((ks << 2) + quad) ^ dg7;
                const bf16x8 vf = *(const bf16x8*)&Vlds[d * VST + (g2 << 3)];
                if (live) accA[nt] = __builtin_amdgcn_mfma_f32_16x16x32_bf16(ef[ks], vf, accA[nt], 0, 0, 0);
                accB[nt] = __builtin_amdgcn_mfma_f32_16x16x32_bf16(pf[ks], vf, accB[nt], 0, 0, 0);
            }
        }
        asm volatile("s_waitcnt lgkmcnt(0)" ::: "memory");
    }

    // ---- epilogue ----
    float g = Gate[h];
    g = 1.f / (1.f + __expf(-g));
    float cA[4], cB[4], nf[4];
    #pragma unroll
    for (int reg = 0; reg < 4; ++reg) {
        const float E = wsum16(eP[reg]);
        const float P = wsum16(pP[reg]);
        cA[reg] = g / E;
        cB[reg] = (1.f - g) / (P + 1e-8f);
        const float Sf = g + (1.f - g) * (P / (P + 1e-8f));
        nf[reg] = 1.f / (Sf + 1e-8f);
    }
    #pragma unroll
    for (int reg = 0; reg < 4; ++reg) {
        const size_t ro = bh_off + (size_t)(l0w + quad * 4 + reg) * 512;
        #pragma unroll
        for (int nt = 0; nt < 4; ++nt) {
            const float o = (cA[reg] * accA[nt][reg] + cB[reg] * accB[nt][reg]) * nf[reg];
            Out[ro + nt * 16 + c16] = o;
        }
    }
}

extern "C" void kernel_launch(void* const* d_in, const int* in_sizes, int n_in,
                              void* d_out, int out_size, void* d_ws, size_t ws_size,
                              hipStream_t stream) {
    const float* Q    = (const float*)d_in[0];
    const float* K    = (const float*)d_in[1];
    const float* V    = (const float*)d_in[2];
    const float* Sig  = (const float*)d_in[3];
    const float* Gate = (const float*)d_in[4];
    // d_in[5] = attn_mask: deterministic causal triu — not read.
    float* Out = (float*)d_out;

    dim3 grid(8 * B_ * H_);   // 1024 blocks: idx = t*128 + bh
    anomaly_attn<<<grid, 256, 0, stream>>>(Q, K, V, Sig, Gate, Out);
}